// Round 10
// baseline (172.564 us; speedup 1.0000x reference)
//
#include <hip/hip_runtime.h>

// InfoCNECauchy: loss = mean_r log(sum_{j!=r} sim[r,j]) - mean_r log(sim[r, r^4096])
// sim = t^2/(d2+t^2), d2 = ||f_r||^2 + ||f_c||^2 - 2<f_r,f_c>, t=0.07
//
// R13: R12's fused 2-launch structure (launch overhead ~20us/launch CONFIRMED
// by R12's gap accounting: 40/59/75us at 2/3/4 launches) with the exit path
// made cheap. R12's regression (gemm 70.6->122us, occupancy 26->17%) is
// attributed to every block's exit doing a same-address fetch_add with a USED
// result: ~768 resident blocks queue on one L3 line at kernel end, each
// holding its CU slot until its RMW round-trips. R13: non-spinner blocks do
// {vmcnt(0) drain, barrier, FIRE-AND-FORGET fetch_add (result unused ->
// atomic-no-return, no stall), retire}. One statically-designated block
// (blockIdx == NTILES-1, dispatched last) sleeps on an agent-scope counter
// load, then reads rowsum/spart via agent-scope loads (bypass stale L2) and
// writes the loss. Release ordering: drain+barrier precede each increment,
// so counter==NTILES => all rowsum atomics are at the coherence point.
// No fences / L2 flushes (R3/R4 poison). K-loop/epilogue = R8 verbatim.

#define N2 8192
#define DIM 512
#define NT 64 /* 8192/128 tiles per dim */
#define NTILES (NT * (NT + 1) / 2)
#define T2 0.0049f

typedef float floatx4 __attribute__((ext_vector_type(4)));
typedef __bf16 bf16x8 __attribute__((ext_vector_type(8)));
typedef __bf16 bf16x4 __attribute__((ext_vector_type(4)));

__device__ __forceinline__ void load_to_lds16(const void* g, void* l) {
  auto gp = (const __attribute__((address_space(1))) void*)(reinterpret_cast<uintptr_t>(g));
  auto lp = (__attribute__((address_space(3))) void*)(reinterpret_cast<uintptr_t>(l));
  __builtin_amdgcn_global_load_lds(gp, lp, 16, 0, 0);
}

// ---- prep: fp32 -> bf16 + row norms + zero rowsum & counter ---------------
__global__ __launch_bounds__(256) void prep_kernel(const float* __restrict__ f,
                                                   __bf16* __restrict__ fbf,
                                                   float* __restrict__ sq,
                                                   float* __restrict__ rowsum,
                                                   int* __restrict__ counter) {
  const int t = threadIdx.x;
  if (t < 2) rowsum[blockIdx.x * 2 + t] = 0.f;
  if (blockIdx.x == 0 && t == 0) *counter = 0;
  const int row = blockIdx.x * 2 + (t >> 7);
  const int ci = (t & 127) * 4;
  const float4 v = *(const float4*)(f + (size_t)row * DIM + ci);
  bf16x4 b;
  b[0] = (__bf16)v.x; b[1] = (__bf16)v.y; b[2] = (__bf16)v.z; b[3] = (__bf16)v.w;
  *(bf16x4*)(fbf + (size_t)row * DIM + ci) = b;
  float s = v.x * v.x + v.y * v.y + v.z * v.z + v.w * v.w;
#pragma unroll
  for (int off = 1; off < 64; off <<= 1) s += __shfl_xor(s, off, 64);
  __shared__ float red[4];
  if ((t & 63) == 0) red[t >> 6] = s;
  __syncthreads();
  if ((t & 127) == 0) sq[row] = red[t >> 6] + red[(t >> 6) + 1];
}

// ---- fused GEMM (upper tri, banded XCD order, BK=64) + epilogue + tail ----
__global__ __launch_bounds__(256) void gemm_kernel(const __bf16* __restrict__ fbf,
                                                   const float* __restrict__ sq,
                                                   float* __restrict__ rowsum,
                                                   float* __restrict__ spart,
                                                   int* __restrict__ counter,
                                                   float* __restrict__ out) {
  // two XOR-swizzled 8KB sub-regions (ks=0/1) per tensor
  __shared__ __bf16 aT[128 * 64];
  __shared__ __bf16 bT[128 * 64];

  // R5's banded tile decode (empirically best): XCD x owns row-bands
  // by in [4x,4x+4) and [60-4x,64-4x), bx-major, 260 tiles each.
  int by, bx;
  {
    const int x = blockIdx.x & 7;
    int kk = blockIdx.x >> 3;
    int band = x;
    const int n1 = 250 - 16 * x;
    if (kk >= n1) { kk -= n1; band = 15 - x; }
    const int by0 = band * 4;
    int bxx = by0;
    int cnt;
    while (kk >= (cnt = min(4, bxx - by0 + 1))) { kk -= cnt; ++bxx; }
    by = by0 + kk;
    bx = bxx;
  }
  const int brow = by * 128;
  const int bcol = bx * 128;
  const bool diag = (by == bx);

  const int t = threadIdx.x;
  const int lane = t & 63;
  const int w = t >> 6;
  const int wrow = (w >> 1) * 64;
  const int wcol = (w & 1) * 64;
  const int q4 = lane >> 4;  // 0..3
  const int lc = lane & 15;  // 0..15

  floatx4 acc[4][4] = {};

  // staging lane -> (global row, 16B chunk) under XOR swizzle (per sub-region):
  // LDS slot (rp, u') holds global (row = rp*2 + (u>>2), chunk = u&3), u = u'^(rp&7)
  int grow[2], gofs[2];
#pragma unroll
  for (int it = 0; it < 2; ++it) {
    const int slot = it * 256 + t;
    const int rp = slot >> 3;
    const int u = (slot & 7) ^ (rp & 7);
    grow[it] = rp * 2 + (u >> 2);
    gofs[it] = (u & 3) * 8;
  }

  // fragment-read swizzle: u = (rr&1)*4+q4, u' = u ^ ((rr>>1)&7); rr = lc here.
  const int up = (((lc & 1) * 4) + q4) ^ (lc >> 1);
  const int rhalf = lc >> 1;

  for (int kt = 0; kt < DIM / 64; ++kt) {
    const int k0 = kt * 64;
#pragma unroll
    for (int it = 0; it < 2; ++it) {
#pragma unroll
      for (int ks = 0; ks < 2; ++ks) {
        load_to_lds16(fbf + (size_t)(brow + grow[it]) * DIM + k0 + ks * 32 + gofs[it],
                      &aT[ks * 4096 + it * 2048 + t * 8]);
        load_to_lds16(fbf + (size_t)(bcol + grow[it]) * DIM + k0 + ks * 32 + gofs[it],
                      &bT[ks * 4096 + it * 2048 + t * 8]);
      }
    }
    __syncthreads();
#pragma unroll
    for (int ks = 0; ks < 2; ++ks) {
      bf16x8 af[4], bfr[4];
#pragma unroll
      for (int mr = 0; mr < 4; ++mr)
        af[mr] = *(const bf16x8*)&aT[ks * 4096 + ((wrow >> 1) + mr * 8 + rhalf) * 64 + up * 8];
#pragma unroll
      for (int mc = 0; mc < 4; ++mc)
        bfr[mc] = *(const bf16x8*)&bT[ks * 4096 + ((wcol >> 1) + mc * 8 + rhalf) * 64 + up * 8];
#pragma unroll
      for (int mr = 0; mr < 4; ++mr)
#pragma unroll
        for (int mc = 0; mc < 4; ++mc)
          acc[mr][mc] =
              __builtin_amdgcn_mfma_f32_16x16x32_bf16(af[mr], bfr[mc], acc[mr][mc], 0, 0, 0);
    }
    __syncthreads();
  }

  // Epilogue. C/D layout: col = lane&15, row = (lane>>4)*4 + reg.
  float sqc[4];
#pragma unroll
  for (int mc = 0; mc < 4; ++mc) sqc[mc] = sq[bcol + wcol + mc * 16 + lc];

  float cs[4] = {0.f, 0.f, 0.f, 0.f};  // column partial sums (off-diag tiles)

#pragma unroll
  for (int mr = 0; mr < 4; ++mr) {
#pragma unroll
    for (int reg = 0; reg < 4; ++reg) {
      const int r = brow + wrow + mr * 16 + q4 * 4 + reg;
      const float sr = sq[r];
      const int pc = r ^ (N2 / 2);
      float rs = 0.f;
#pragma unroll
      for (int mc = 0; mc < 4; ++mc) {
        const int c = bcol + wcol + mc * 16 + lc;
        const float g = acc[mr][mc][reg];
        const float d2 = fmaxf(sr + sqc[mc] - 2.f * g, 0.f);
        const float s = T2 * __builtin_amdgcn_rcpf(d2 + T2);
        if (c != r) rs += s;  // diagonal excluded exactly (diag tiles only)
        cs[mc] += s;          // unused on diag tiles
        if (c == pc) {        // off-diag only, 1 lane; agent-scope store (bypass L2)
          __hip_atomic_store(&spart[r], s, __ATOMIC_RELAXED, __HIP_MEMORY_SCOPE_AGENT);
          __hip_atomic_store(&spart[pc], s, __ATOMIC_RELAXED, __HIP_MEMORY_SCOPE_AGENT);
        }
      }
#pragma unroll
      for (int off = 1; off < 16; off <<= 1) rs += __shfl_xor(rs, off, 64);
      if (lc == 0) atomicAdd(&rowsum[r], rs);
    }
  }

  if (!diag) {
#pragma unroll
    for (int mc = 0; mc < 4; ++mc) {
      float v = cs[mc];
      v += __shfl_xor(v, 16, 64);
      v += __shfl_xor(v, 32, 64);
      if (lane < 16) atomicAdd(&rowsum[bcol + wcol + mc * 16 + lane], v);
    }
  }

  // ---- cheap exit + designated-spinner tail (saves one kernel launch) -----
  // Release: drain this wave's VMEM (rowsum atomics / spart stores) to the
  // coherence point, barrier so all the block's waves drained, then a
  // FIRE-AND-FORGET increment (result unused -> atomic-no-return, no stall).
  asm volatile("s_waitcnt vmcnt(0)" ::: "memory");
  __syncthreads();
  if (t == 0)
    __hip_atomic_fetch_add(counter, 1, __ATOMIC_RELAXED, __HIP_MEMORY_SCOPE_AGENT);

  if (blockIdx.x == NTILES - 1) {  // dispatched last -> shortest spin
    if (t == 0) {
      while (__hip_atomic_load(counter, __ATOMIC_RELAXED, __HIP_MEMORY_SCOPE_AGENT) < NTILES)
        __builtin_amdgcn_s_sleep(8);
    }
    __syncthreads();
    asm volatile("" ::: "memory");  // pin tail loads after the spin
    float a = 0.f;
    for (int r = t; r < N2; r += 256) {
      const float rsv =
          __hip_atomic_load(&rowsum[r], __ATOMIC_RELAXED, __HIP_MEMORY_SCOPE_AGENT);
      const float spv =
          __hip_atomic_load(&spart[r], __ATOMIC_RELAXED, __HIP_MEMORY_SCOPE_AGENT);
      a += logf(rsv) - logf(spv);
    }
#pragma unroll
    for (int off = 1; off < 64; off <<= 1) a += __shfl_xor(a, off, 64);
    float* red = (float*)aT;  // reuse LDS (no extra allocation)
    if ((t & 63) == 0) red[t >> 6] = a;
    __syncthreads();
    if (t == 0) out[0] = (red[0] + red[1] + red[2] + red[3]) * (1.0f / (float)N2);
  }
}

extern "C" void kernel_launch(void* const* d_in, const int* in_sizes, int n_in,
                              void* d_out, int out_size, void* d_ws, size_t ws_size,
                              hipStream_t stream) {
  const float* features = (const float*)d_in[0];
  float* out = (float*)d_out;

  char* ws = (char*)d_ws;
  __bf16* fbf = (__bf16*)ws;                                     // 8 MB
  float* sq = (float*)(ws + (size_t)N2 * DIM * sizeof(__bf16));  // 32 KB
  float* rowsum = sq + N2;                                       // 32 KB
  float* spart = rowsum + N2;                                    // 32 KB
  int* counter = (int*)(spart + N2);                             // 4 B

  prep_kernel<<<N2 / 2, 256, 0, stream>>>(features, fbf, sq, rowsum, counter);
  gemm_kernel<<<NTILES, 256, 0, stream>>>(fbf, sq, rowsum, spart, counter, out);
}

// Round 12
// 145.076 us; speedup vs baseline: 1.1895x; 1.1895x over previous
//
#include <hip/hip_runtime.h>

// InfoCNECauchy: loss = mean_r log(sum_{j!=r} sim[r,j]) - mean_r log(sim[r, r^4096])
// sim = t^2/(d2+t^2), d2 = ||f_r||^2 + ||f_c||^2 - 2<f_r,f_c>, t=0.07
//
// R14 (resubmit; R11-round bench was a GPUAcquisitionTimeout, experiment
// never ran): 256^2 tiles with the PROVEN 2-barrier loop body. Cross-round
// roofline: R5/R8/R9/R10 all pin at 6.5-7.5 TB/s of logical panel-read
// throughput (532MB/70us etc.) = L3/Infinity-fabric BW class (fbf 8MB
// L3-resident, FETCH~26MB) => gemm is L3-BW-bound on panel reads. Explains
// all six prior falsifications (BW-bound: barriers/waves/occupancy/atomics
// irrelevant). Fix: halve panel bytes via 256^2 tiles (532->272MB). R6's
// 256^2 failure was its 8-phase port + 8 waves; here: R8/R9 body verbatim
// (XOR swizzles parameterized by 128-row region), 1024 thr / 16 waves,
// per-wave 64x64 (same acc shape as R8, VGPR ~100 -> 16 waves/CU). LDS 64KB.
// Granularity: 512 full tiles = exactly 2 rounds; 16 leftover tiles run as
// 64 quarter (128^2) blocks via the R9 body (waves 0-7 compute, all barrier),
// dispatched last. Diag-tile lower quad: 1 dead block (early exit,
// pre-barrier). Fusion/spinner abandoned (R12/R13: release-drain of
// contended atomics costs more than the launch it saves). 3-launch restored.

#define N2 8192
#define DIM 512
#define NT2 32   /* 256-tiles per dim */
#define NFULL 512
#define NGRID 576
#define T2 0.0049f

typedef float floatx4 __attribute__((ext_vector_type(4)));
typedef __bf16 bf16x8 __attribute__((ext_vector_type(8)));
typedef __bf16 bf16x4 __attribute__((ext_vector_type(4)));

__device__ __forceinline__ void load_to_lds16(const void* g, void* l) {
  auto gp = (const __attribute__((address_space(1))) void*)(reinterpret_cast<uintptr_t>(g));
  auto lp = (__attribute__((address_space(3))) void*)(reinterpret_cast<uintptr_t>(l));
  __builtin_amdgcn_global_load_lds(gp, lp, 16, 0, 0);
}

// ---- prep: fp32 -> bf16 + row norms + zero rowsum ------------------------
__global__ __launch_bounds__(256) void prep_kernel(const float* __restrict__ f,
                                                   __bf16* __restrict__ fbf,
                                                   float* __restrict__ sq,
                                                   float* __restrict__ rowsum) {
  const int t = threadIdx.x;
  if (t < 2) rowsum[blockIdx.x * 2 + t] = 0.f;
  const int row = blockIdx.x * 2 + (t >> 7);
  const int ci = (t & 127) * 4;
  const float4 v = *(const float4*)(f + (size_t)row * DIM + ci);
  bf16x4 b;
  b[0] = (__bf16)v.x; b[1] = (__bf16)v.y; b[2] = (__bf16)v.z; b[3] = (__bf16)v.w;
  *(bf16x4*)(fbf + (size_t)row * DIM + ci) = b;
  float s = v.x * v.x + v.y * v.y + v.z * v.z + v.w * v.w;
#pragma unroll
  for (int off = 1; off < 64; off <<= 1) s += __shfl_xor(s, off, 64);
  __shared__ float red[4];
  if ((t & 63) == 0) red[t >> 6] = s;
  __syncthreads();
  if ((t & 127) == 0) sq[row] = red[t >> 6] + red[(t >> 6) + 1];
}

// ---- fused GEMM (upper tri of 256^2 tiles, banded XCD order) + epilogue ---
__global__ __launch_bounds__(1024, 4) void gemm_kernel(const __bf16* __restrict__ fbf,
                                                       const float* __restrict__ sq,
                                                       float* __restrict__ rowsum,
                                                       float* __restrict__ spart) {
  // per-tensor: 4 XOR-swizzled 8KB regions [rh(0/1) x ks(0/1)]
  __shared__ __bf16 aT[4 * 4096];
  __shared__ __bf16 bT[4 * 4096];

  // Banded decode over NT2=32 (R6-proven): XCD x owns bands x and 15-x
  // (bands of 2 tile-rows), 66 tiles each, bx-major. k=0..63 -> full 256^2
  // blocks; k=64,65 -> leftover tiles, run as 4 quarter (128^2) blocks.
  int by, bx, quad = -1;
  {
    const int x = blockIdx.x & 7;
    int kk;
    if (blockIdx.x < NFULL) {
      kk = blockIdx.x >> 3;                    // 0..63
    } else {
      const int j = (blockIdx.x - NFULL) >> 3; // 0..7
      kk = 64 + (j >> 2);
      quad = j & 3;
    }
    int band = x;
    const int n1 = 63 - 4 * x;
    if (kk >= n1) { kk -= n1; band = 15 - x; }
    const int by0 = band * 2;
    int bxx = by0;
    int cnt;
    while (kk >= (cnt = min(2, bxx - by0 + 1))) { kk -= cnt; ++bxx; }
    by = by0 + kk;
    bx = bxx;
  }

  const int t = threadIdx.x;
  const int lane = t & 63;
  const int w = t >> 6;
  const int q4 = lane >> 4;  // 0..3
  const int lc = lane & 15;  // 0..15
  // fragment-read swizzle (proven): u = (rr&1)*4+q4, u' = u ^ ((rr>>1)&7)
  const int up = (((lc & 1) * 4) + q4) ^ (lc >> 1);
  const int rhalf = lc >> 1;

  if (quad < 0) {
    // ================= full 256^2 path (16 waves) =================
    const int brow = by * 256;
    const int bcol = bx * 256;
    const bool diag = (brow == bcol);
    const int wrow = (w >> 2) * 64;   // 0,64,128,192
    const int wcol = (w & 3) * 64;    // 0,64,128,192
    const int rhA = wrow >> 7, rhB = wcol >> 7;
    const int rbA = (wrow >> 1) & 63, rbB = (wcol >> 1) & 63;

    // staging map (R9-proven, per 512-slot region; rh = upper bit of t)
    const int rh = t >> 9;
    const int s = t & 511;
    const int rp = s >> 3;
    const int u = (s & 7) ^ (rp & 7);
    const int grow = rh * 128 + rp * 2 + (u >> 2);
    const int gofs = (u & 3) * 8;

    floatx4 acc[4][4] = {};

    for (int kt = 0; kt < DIM / 64; ++kt) {
      const int k0 = kt * 64;
#pragma unroll
      for (int ks = 0; ks < 2; ++ks) {
        load_to_lds16(fbf + (size_t)(brow + grow) * DIM + k0 + ks * 32 + gofs,
                      &aT[(rh * 2 + ks) * 4096 + s * 8]);
        load_to_lds16(fbf + (size_t)(bcol + grow) * DIM + k0 + ks * 32 + gofs,
                      &bT[(rh * 2 + ks) * 4096 + s * 8]);
      }
      __syncthreads();
#pragma unroll
      for (int ks = 0; ks < 2; ++ks) {
        bf16x8 af[4], bfr[4];
#pragma unroll
        for (int mr = 0; mr < 4; ++mr)
          af[mr] = *(const bf16x8*)&aT[(rhA * 2 + ks) * 4096 +
                                       (rbA + mr * 8 + rhalf) * 64 + up * 8];
#pragma unroll
        for (int mc = 0; mc < 4; ++mc)
          bfr[mc] = *(const bf16x8*)&bT[(rhB * 2 + ks) * 4096 +
                                        (rbB + mc * 8 + rhalf) * 64 + up * 8];
#pragma unroll
        for (int mr = 0; mr < 4; ++mr)
#pragma unroll
          for (int mc = 0; mc < 4; ++mc)
            acc[mr][mc] =
                __builtin_amdgcn_mfma_f32_16x16x32_bf16(af[mr], bfr[mc], acc[mr][mc], 0, 0, 0);
      }
      __syncthreads();
    }

    // Epilogue (R8 verbatim). C/D layout: col = lane&15, row = (lane>>4)*4+reg.
    float sqc[4];
#pragma unroll
    for (int mc = 0; mc < 4; ++mc) sqc[mc] = sq[bcol + wcol + mc * 16 + lc];
    float cs[4] = {0.f, 0.f, 0.f, 0.f};
#pragma unroll
    for (int mr = 0; mr < 4; ++mr) {
#pragma unroll
      for (int reg = 0; reg < 4; ++reg) {
        const int r = brow + wrow + mr * 16 + q4 * 4 + reg;
        const float sr = sq[r];
        const int pc = r ^ (N2 / 2);
        float rs = 0.f;
#pragma unroll
        for (int mc = 0; mc < 4; ++mc) {
          const int c = bcol + wcol + mc * 16 + lc;
          const float g = acc[mr][mc][reg];
          const float d2 = fmaxf(sr + sqc[mc] - 2.f * g, 0.f);
          const float sv = T2 * __builtin_amdgcn_rcpf(d2 + T2);
          if (c != r) rs += sv;
          cs[mc] += sv;
          if (c == pc) { spart[r] = sv; spart[pc] = sv; }
        }
#pragma unroll
        for (int off = 1; off < 16; off <<= 1) rs += __shfl_xor(rs, off, 64);
        if (lc == 0) atomicAdd(&rowsum[r], rs);
      }
    }
    if (!diag) {
#pragma unroll
      for (int mc = 0; mc < 4; ++mc) {
        float v = cs[mc];
        v += __shfl_xor(v, 16, 64);
        v += __shfl_xor(v, 32, 64);
        if (lane < 16) atomicAdd(&rowsum[bcol + wcol + mc * 16 + lane], v);
      }
    }
  } else {
    // ================= quarter 128^2 path (R9 body; waves 0-7) =============
    if (by == bx && quad == 2) return;  // transpose-covered; exits pre-barrier
    const int brow = by * 256 + (quad >> 1) * 128;
    const int bcol = bx * 256 + (quad & 1) * 128;
    const bool diag = (brow == bcol);
    const int wrow = (w >> 2) * 64;     // waves 0-7: 0 or 64
    const int wcol = (w & 3) * 32;      // 0,32,64,96

    int grow = 0, gofs = 0;
    if (t < 512) {
      const int rp = t >> 3;
      const int u = (t & 7) ^ (rp & 7);
      grow = rp * 2 + (u >> 2);
      gofs = (u & 3) * 8;
    }

    floatx4 acc[4][2] = {};

    for (int kt = 0; kt < DIM / 64; ++kt) {
      const int k0 = kt * 64;
      if (t < 512) {
#pragma unroll
        for (int ks = 0; ks < 2; ++ks) {
          load_to_lds16(fbf + (size_t)(brow + grow) * DIM + k0 + ks * 32 + gofs,
                        &aT[ks * 4096 + t * 8]);
          load_to_lds16(fbf + (size_t)(bcol + grow) * DIM + k0 + ks * 32 + gofs,
                        &bT[ks * 4096 + t * 8]);
        }
      }
      __syncthreads();
      if (w < 8) {
#pragma unroll
        for (int ks = 0; ks < 2; ++ks) {
          bf16x8 af[4], bfr[2];
#pragma unroll
          for (int mr = 0; mr < 4; ++mr)
            af[mr] = *(const bf16x8*)&aT[ks * 4096 + ((wrow >> 1) + mr * 8 + rhalf) * 64 + up * 8];
#pragma unroll
          for (int mc = 0; mc < 2; ++mc)
            bfr[mc] = *(const bf16x8*)&bT[ks * 4096 + ((wcol >> 1) + mc * 8 + rhalf) * 64 + up * 8];
#pragma unroll
          for (int mr = 0; mr < 4; ++mr)
#pragma unroll
            for (int mc = 0; mc < 2; ++mc)
              acc[mr][mc] =
                  __builtin_amdgcn_mfma_f32_16x16x32_bf16(af[mr], bfr[mc], acc[mr][mc], 0, 0, 0);
        }
      }
      __syncthreads();
    }

    if (w < 8) {
      float sqc[2];
#pragma unroll
      for (int mc = 0; mc < 2; ++mc) sqc[mc] = sq[bcol + wcol + mc * 16 + lc];
      float cs[2] = {0.f, 0.f};
#pragma unroll
      for (int mr = 0; mr < 4; ++mr) {
#pragma unroll
        for (int reg = 0; reg < 4; ++reg) {
          const int r = brow + wrow + mr * 16 + q4 * 4 + reg;
          const float sr = sq[r];
          const int pc = r ^ (N2 / 2);
          float rs = 0.f;
#pragma unroll
          for (int mc = 0; mc < 2; ++mc) {
            const int c = bcol + wcol + mc * 16 + lc;
            const float g = acc[mr][mc][reg];
            const float d2 = fmaxf(sr + sqc[mc] - 2.f * g, 0.f);
            const float sv = T2 * __builtin_amdgcn_rcpf(d2 + T2);
            if (c != r) rs += sv;
            cs[mc] += sv;
            if (c == pc) { spart[r] = sv; spart[pc] = sv; }
          }
#pragma unroll
          for (int off = 1; off < 16; off <<= 1) rs += __shfl_xor(rs, off, 64);
          if (lc == 0) atomicAdd(&rowsum[r], rs);
        }
      }
      if (!diag) {
#pragma unroll
        for (int mc = 0; mc < 2; ++mc) {
          float v = cs[mc];
          v += __shfl_xor(v, 16, 64);
          v += __shfl_xor(v, 32, 64);
          if (lane < 16) atomicAdd(&rowsum[bcol + wcol + mc * 16 + lane], v);
        }
      }
    }
  }
}

// ---- final scalar reduction ---------------------------------------------
__global__ __launch_bounds__(256) void final_kernel(const float* __restrict__ rowsum,
                                                    const float* __restrict__ spart,
                                                    float* __restrict__ out) {
  const int t = threadIdx.x;
  float a = 0.f;
  for (int r = t; r < N2; r += 256) a += logf(rowsum[r]) - logf(spart[r]);
#pragma unroll
  for (int off = 1; off < 64; off <<= 1) a += __shfl_xor(a, off, 64);
  __shared__ float red[4];
  if ((t & 63) == 0) red[t >> 6] = a;
  __syncthreads();
  if (t == 0) out[0] = (red[0] + red[1] + red[2] + red[3]) * (1.0f / (float)N2);
}

extern "C" void kernel_launch(void* const* d_in, const int* in_sizes, int n_in,
                              void* d_out, int out_size, void* d_ws, size_t ws_size,
                              hipStream_t stream) {
  const float* features = (const float*)d_in[0];
  float* out = (float*)d_out;

  char* ws = (char*)d_ws;
  __bf16* fbf = (__bf16*)ws;                                     // 8 MB
  float* sq = (float*)(ws + (size_t)N2 * DIM * sizeof(__bf16));  // 32 KB
  float* rowsum = sq + N2;                                       // 32 KB
  float* spart = rowsum + N2;                                    // 32 KB

  prep_kernel<<<N2 / 2, 256, 0, stream>>>(features, fbf, sq, rowsum);
  gemm_kernel<<<NGRID, 1024, 0, stream>>>(fbf, sq, rowsum, spart);
  final_kernel<<<1, 256, 0, stream>>>(rowsum, spart, out);
}